// Round 7
// baseline (227.460 us; speedup 1.0000x reference)
//
#include <hip/hip_runtime.h>
#include <math.h>

typedef int intx4 __attribute__((ext_vector_type(4)));
typedef int intx8 __attribute__((ext_vector_type(8)));
typedef float floatx16 __attribute__((ext_vector_type(16)));

#define N_ROWS 8192
#define KDIM 1024

// E8M0 scale bytes: 123 -> 2^-4 per side (data pre-scaled by 2^4 each side)
#define SCALE_WORD 0x7B7B7B7B

// order-preserving float->int encoding for atomicMax
__device__ __forceinline__ int fenc(float f) {
  int i = __float_as_int(f);
  return i >= 0 ? i : (i ^ 0x7fffffff);
}
__device__ __forceinline__ float fdec(int e) {
  int b = e >= 0 ? e : (e ^ 0x7fffffff);
  return __int_as_float(b);
}

// async 16B global->LDS DMA (m97 pattern: per-lane global src, LDS dest must
// equal wave-uniform base + lane*16 -- ours does by construction).
__device__ __forceinline__ void gld_lds16(const void* g, void* l) {
  __builtin_amdgcn_global_load_lds(
      (const __attribute__((address_space(1))) unsigned int*)g,
      (__attribute__((address_space(3))) unsigned int*)l, 16, 0, 0);
}

// One WAVE per row (4 rows/block, no __syncthreads): computes 1/||x|| (fp32),
// writes row normalized*16 as e4m3 via HW cvt, inits the max slot.
__global__ __launch_bounds__(256) void normalize_kernel(
    const float* __restrict__ ex, const float* __restrict__ ey,
    unsigned char* __restrict__ exn, unsigned char* __restrict__ eyn,
    int* __restrict__ rowmax, int* __restrict__ colmax) {
  const int wave = threadIdx.x >> 6, lane = threadIdx.x & 63;
  const int gr = blockIdx.x * 4 + wave;  // 0..16383
  const float* x;
  unsigned char* out;
  int* mslot;
  int row;
  if (gr < N_ROWS) {
    x = ex; out = exn; mslot = rowmax; row = gr;
  } else {
    x = ey; out = eyn; mslot = colmax; row = gr - N_ROWS;
  }
  const float4* xr = (const float4*)(x + (size_t)row * KDIM);
  float4 v[4];
  float ss = 0.f;
#pragma unroll
  for (int j = 0; j < 4; ++j) {
    v[j] = xr[lane + j * 64];  // coalesced
    ss += v[j].x * v[j].x + v[j].y * v[j].y + v[j].z * v[j].z + v[j].w * v[j].w;
  }
#pragma unroll
  for (int off = 32; off > 0; off >>= 1) ss += __shfl_xor(ss, off, 64);
  const float rs = 16.0f * rsqrtf(fmaxf(ss, 1e-24f));  // 2^4 pre-scale
  int* op = (int*)(out + (size_t)row * KDIM);
#pragma unroll
  for (int j = 0; j < 4; ++j) {
    int w = __builtin_amdgcn_cvt_pk_fp8_f32(v[j].x * rs, v[j].y * rs, 0, false);
    w = __builtin_amdgcn_cvt_pk_fp8_f32(v[j].z * rs, v[j].w * rs, w, true);
    op[lane + j * 64] = w;
  }
  if (lane == 0) mslot[row] = (int)0x80000000;  // encoded -inf floor
}

// 128x128 tile GEMM (A @ B^T, row-major K-contiguous e4m3) using MX-scaled
// mfma_scale_f32_32x32x64_f8f6f4, fused with row/col max reduction.
//
// Round-18 change: fine-grained phase schedule (T3 proper) on r17's data
// paths. Null-ledger: r15 (removed LDS write-issue) = r17 (counted vmcnt,
// 2-deep) = r11 = ~119 us; r13/r16 (A-direct) = 177. This reproduces the
// documented regime gate: counted-vmcnt alone is null at 2-phase because
// the coarse stage->bar->compute convoy IS the critical path (m233); the
// escape is the per-phase interleave (m201), which needs:
//  1) 3-buffer LDS rotation (48 KB): stage tile t+2 into buf (t+2)%3 while
//     reading buf t%3 -- kills the overwrite race that forced stage-issue
//     to sit after COMPUTE; staging now interleaves INTO the phases.
//  2) 2 phases per K-tile, each {ds_reads for 2-MFMA cluster || 2 stage
//     DMAs} -> s_barrier -> lgkmcnt(0)+sched_barrier -> setprio(1) ->
//     2 MFMA -> setprio(0) -> barrier. Phase 0: aF0,aF1,bF0 + stage-A;
//     phase 1: bF1 + stage-B.
//  3) vmcnt(4) once per tile (tail): retires tile t+1's 4 DMAs; t+2's
//     stay in flight across all barriers. Only drain: tile-14 tail.
// Hazards: buf b staged at tile t was last read at t-1 (trailing barrier
// precedes stage issue); avail = own vmcnt(4) + barrier (in-order
// retirement, cross-wave join); ds_reads are compiler-visible loads.
// Data paths byte-identical to r15/r17 -> absmax 0.0 preserved.
// Tripwires: WRITE_SIZE ~20-24 MB (spill), VGPR ~64, LDS 49152, occ ~3
// blocks/CU. If null: 128^2/4-wave can't express the schedule -> next is
// the 256^2/8-wave acc[4][2] redesign.
//
// LDS swizzle (verified r8): 64-B rows, 16-B chunk c of row r at slot
// c ^ ((r>>1)&3); staging pre-swizzles the global source chunk so the
// linear lane*16 dest lands swizzle-stored; fragment reads recover true
// chunk 2h+j -> operand bytes at (half,j,b) equal global k=k0+(2h+j)*16+b
// for BOTH A and B -> exact dot-product pairing (absmax 0.0 thru r17).
__global__ __launch_bounds__(256, 4) void gemm_max_kernel(
    const unsigned char* __restrict__ A, const unsigned char* __restrict__ B,
    int* __restrict__ rowmax, int* __restrict__ colmax) {
  constexpr int TM = 128, BK = 64, K = KDIM;
  constexpr int BUF = TM * BK;                          // 8 KB per buffer
  __shared__ __align__(16) unsigned char sA[3 * BUF];   // 24 KB (3-buf)
  __shared__ __align__(16) unsigned char sB[3 * BUF];   // 24 KB

  const int bm = blockIdx.x, bn = blockIdx.y;
  const int tid = threadIdx.x;
  const int lane = tid & 63, wave = tid >> 6;
  const int wm = wave >> 1, wn = wave & 1;  // 2x2 waves of 64x64
  const int l32 = lane & 31, half = lane >> 5;
  const int fsw = (l32 >> 1) & 3;                 // f(row) = (row>>1)&3
  const int oLo = (((2 * half + 0) ^ fsw) << 4);  // swizzled slot offsets
  const int oHi = (((2 * half + 1) ^ fsw) << 4);

  const char* Ab = (const char*)(A + (size_t)bm * TM * K);
  const char* Bb = (const char*)(B + (size_t)bn * TM * K);

  floatx16 acc[2][2] = {};

  // Staging: wave w stages rows w*32..+31 of each tile per step (2 DMAs
  // per array per lane). Dest (linear lane*16): row r_d = wave*32 +
  // (lane>>2), slot lane&3. Source chunk = (lane&3) ^ f(r_d); the +16-row
  // second DMA keeps the same offset (f(r+16)==f(r)).
  const int src_c16 = (((lane & 3) ^ ((lane >> 3) & 3)) << 4);
  const char* gA = Ab + (size_t)(wave * 32 + (lane >> 2)) * K + src_c16;
  const char* gB = Bb + (size_t)(wave * 32 + (lane >> 2)) * K + src_c16;
  unsigned char* wA = sA + wave * 2048 + lane * 16;  // linear per-lane dest
  unsigned char* wB = sB + wave * 2048 + lane * 16;

#define WAITV(N)                                          \
  do {                                                    \
    asm volatile("s_waitcnt vmcnt(" #N ")" ::: "memory"); \
    __builtin_amdgcn_sched_barrier(0);                    \
  } while (0)

  // swizzle-recovering 16B-pair fragment read (byte math identical to r15)
#define RD8(p)                                                        \
  ({                                                                  \
    const intx4 lo_ = *(const intx4*)((p) + oLo);                     \
    const intx4 hi_ = *(const intx4*)((p) + oHi);                     \
    __builtin_shufflevector(lo_, hi_, 0, 1, 2, 3, 4, 5, 6, 7);        \
  })

#define MFMA(d, a, b)                                                 \
  d = __builtin_amdgcn_mfma_scale_f32_32x32x64_f8f6f4(                \
      (a), (b), (d), 0, 0, 0, SCALE_WORD, 0, SCALE_WORD)

  // One K-tile: 2 phases, each {reads || stage-half; bar; lgkm0; prio;
  // 2 MFMA; prio0; bar}. TAILN: 4 = steady vmcnt(4)+bar; 0 = drain+bar
  // (tile 14); -1 = nothing (tile 15).
#define TILE(bufr, bufw, DO_STAGE, k2, TAILN)                               \
  do {                                                                      \
    const unsigned char* aP0 = &sA[(bufr)*BUF + (wm * 64 + l32) * BK];      \
    const unsigned char* aP1 = aP0 + 32 * BK;                               \
    const unsigned char* bP0 = &sB[(bufr)*BUF + (wn * 64 + l32) * BK];      \
    const unsigned char* bP1 = bP0 + 32 * BK;                               \
    /* phase 0 */                                                           \
    const intx8 aF0 = RD8(aP0);                                             \
    const intx8 aF1 = RD8(aP1);                                             \
    const intx8 bF0 = RD8(bP0);                                             \
    if (DO_STAGE) {                                                         \
      gld_lds16(gA + (size_t)(k2), wA + (bufw)*BUF);                        \
      gld_lds16(gA + (size_t)(k2) + 16 * (size_t)K, wA + (bufw)*BUF + 1024);\
    }                                                                       \
    __builtin_amdgcn_s_barrier();                                           \
    asm volatile("s_waitcnt lgkmcnt(0)" ::: "memory");                      \
    __builtin_amdgcn_sched_barrier(0);                                      \
    __builtin_amdgcn_s_setprio(1);                                          \
    MFMA(acc[0][0], aF0, bF0);                                              \
    MFMA(acc[1][0], aF1, bF0);                                              \
    __builtin_amdgcn_s_setprio(0);                                          \
    __builtin_amdgcn_s_barrier();                                           \
    /* phase 1 */                                                           \
    const intx8 bF1 = RD8(bP1);                                             \
    if (DO_STAGE) {                                                         \
      gld_lds16(gB + (size_t)(k2), wB + (bufw)*BUF);                        \
      gld_lds16(gB + (size_t)(k2) + 16 * (size_t)K, wB + (bufw)*BUF + 1024);\
    }                                                                       \
    __builtin_amdgcn_s_barrier();                                           \
    asm volatile("s_waitcnt lgkmcnt(0)" ::: "memory");                      \
    __builtin_amdgcn_sched_barrier(0);                                      \
    __builtin_amdgcn_s_setprio(1);                                          \
    MFMA(acc[0][1], aF0, bF1);                                              \
    MFMA(acc[1][1], aF1, bF1);                                              \
    __builtin_amdgcn_s_setprio(0);                                          \
    if ((TAILN) == 4) {                                                     \
      WAITV(4);                                                             \
      __builtin_amdgcn_s_barrier();                                         \
    } else if ((TAILN) == 0) {                                              \
      WAITV(0);                                                             \
      __builtin_amdgcn_s_barrier();                                         \
    }                                                                       \
  } while (0)

#define STAGE4(k0, buf)                                                    \
  do {                                                                     \
    gld_lds16(gA + (size_t)(k0), wA + (buf)*BUF);                          \
    gld_lds16(gA + (size_t)(k0) + 16 * (size_t)K, wA + (buf)*BUF + 1024);  \
    gld_lds16(gB + (size_t)(k0), wB + (buf)*BUF);                          \
    gld_lds16(gB + (size_t)(k0) + 16 * (size_t)K, wB + (buf)*BUF + 1024);  \
  } while (0)

  // Prologue: tiles 0,1 in flight (8 DMAs); retire tile 0's, join.
  STAGE4(0, 0);
  STAGE4(BK, 1);
  WAITV(4);
  __builtin_amdgcn_s_barrier();

  // Steady state, buffers rotate 0,1,2; tile t stages tile t+2 into
  // buf (t+2)%3 (= the buffer tile t-1 just finished reading).
#pragma unroll 1
  for (int t = 0; t < 12; t += 3) {
    TILE(0, 2, 1, (size_t)(t + 2) * BK, 4);
    TILE(1, 0, 1, (size_t)(t + 3) * BK, 4);
    TILE(2, 1, 1, (size_t)(t + 4) * BK, 4);
  }
  TILE(0, 2, 1, (size_t)14 * BK, 4);  // tile 12, stages 14
  TILE(1, 0, 1, (size_t)15 * BK, 4);  // tile 13, stages 15
  TILE(2, 0, 0, 0, 0);                // tile 14, drain 15's DMAs
  TILE(0, 0, 0, 0, -1);               // tile 15

#undef TILE
#undef STAGE4
#undef RD8
#undef MFMA
#undef WAITV

  // 32x32 C/D layout (m74/m101, dtype-independent):
  //   col = lane&31, row = (reg&3) + 8*(reg>>2) + 4*(lane>>5), reg in [0,16)
  // Row maxes: in-lane over ni, shuffle across 32 cols (masks 1..16 stay
  // within a half), l32==0 lanes write.
#pragma unroll
  for (int mi = 0; mi < 2; ++mi) {
#pragma unroll
    for (int reg = 0; reg < 16; ++reg) {
      float v = fmaxf(acc[mi][0][reg], acc[mi][1][reg]);
#pragma unroll
      for (int m = 1; m < 32; m <<= 1) v = fmaxf(v, __shfl_xor(v, m, 64));
      if (l32 == 0) {
        const int grow = bm * TM + wm * 64 + mi * 32 +
                         (reg & 3) + 8 * (reg >> 2) + 4 * half;
        atomicMax(&rowmax[grow], fenc(v));
      }
    }
  }
  // Col maxes: in-lane over mi,reg (32 vals), combine halves via xor 32.
#pragma unroll
  for (int ni = 0; ni < 2; ++ni) {
    float v = -3.402823466e38f;
#pragma unroll
    for (int mi = 0; mi < 2; ++mi)
#pragma unroll
      for (int reg = 0; reg < 16; ++reg) v = fmaxf(v, acc[mi][ni][reg]);
    v = fmaxf(v, __shfl_xor(v, 32, 64));
    if (half == 0) {
      const int gcol = bn * TM + wn * 64 + ni * 32 + l32;
      atomicMax(&colmax[gcol], fenc(v));
    }
  }
}

__global__ __launch_bounds__(1024) void finalize_kernel(
    const int* __restrict__ rowmax, const int* __restrict__ colmax,
    float* __restrict__ out) {
  const int tid = threadIdx.x;
  float s1 = 0.f, s2 = 0.f;
  for (int i = tid; i < N_ROWS; i += 1024) {
    s1 += 1.0f - fdec(rowmax[i]);
    s2 += 1.0f - fdec(colmax[i]);
  }
#pragma unroll
  for (int off = 32; off > 0; off >>= 1) {
    s1 += __shfl_down(s1, off, 64);
    s2 += __shfl_down(s2, off, 64);
  }
  __shared__ float r1[16], r2[16];
  if ((tid & 63) == 0) {
    r1[tid >> 6] = s1;
    r2[tid >> 6] = s2;
  }
  __syncthreads();
  if (tid == 0) {
    const double SIGMA = 0.3;
    const double H_CONST = 0.5 * log(2.0 * 3.14159265358979323846 * SIGMA * SIGMA) + 0.5;
    const float HS = (float)(H_CONST / SIGMA);
    float a1 = 0.f, a2 = 0.f;
#pragma unroll
    for (int w = 0; w < 16; ++w) {
      a1 += r1[w];
      a2 += r2[w];
    }
    out[0] = HS * a1;
    out[1] = HS * a2;
  }
}

extern "C" void kernel_launch(void* const* d_in, const int* in_sizes, int n_in,
                              void* d_out, int out_size, void* d_ws, size_t ws_size,
                              hipStream_t stream) {
  const float* ex = (const float*)d_in[0];
  const float* ey = (const float*)d_in[1];
  float* out = (float*)d_out;
  char* ws = (char*)d_ws;

  unsigned char* exn = (unsigned char*)ws;                                   // 8 MB
  unsigned char* eyn = (unsigned char*)(ws + (size_t)N_ROWS * KDIM);         // 8 MB
  int* rowmax = (int*)(ws + (size_t)N_ROWS * KDIM * 2);                      // 32 KB
  int* colmax = rowmax + N_ROWS;                                             // 32 KB

  normalize_kernel<<<2 * N_ROWS / 4, 256, 0, stream>>>(ex, ey, exn, eyn, rowmax, colmax);
  gemm_max_kernel<<<dim3(64, 64), 256, 0, stream>>>(exn, eyn, rowmax, colmax);
  finalize_kernel<<<1, 1024, 0, stream>>>(rowmax, colmax, out);
}